// Round 1
// 412.763 us; speedup vs baseline: 1.0538x; 1.0538x over previous
//
#include <hip/hip_runtime.h>

// =====================================================================
// QuadraticChargesEnergyReadout — R4: direct-streaming rewrite.
// R3 was latency/serialization-bound at 1.08 TB/s (13.6% HBM, VALU 6%):
// column-striped tiles issued 128 B-per-row @2 KB-stride bursts with a
// full vmcnt(0)+barrier drain every 16 KB (pipeline depth = 1 tile).
// R4 removes LDS entirely: 32 lanes per node, each lane owns contiguous
// features [4s,4s+4) (s: 1 float4, v: 3 float4 = 12 floats = 4 whole
// features, phases compile-time). The Ms/Mv coefficients depend only on
// lane&31 -> 60 loop-invariant registers per lane. Every row of
// node_feats is read exactly once, front to back; reduction is 5
// shfl_xor within the 32-lane group. No barriers, no waitcnt drains.
// Memory-bound: ~271 MB traffic, roofline ~43 us.
// =====================================================================

#define NNODES 131072
#define TBLK 256
#define NODES_PER_PASS 8          // (TBLK/32) nodes per block-pass
#define PASSES 8
#define NPB (NODES_PER_PASS * PASSES)   // 64 nodes per block

// ---------------- precompute 1: per-block partial coefficients --------
// partial[b][k][w], k 0..5 = s.s monomials {a2,ab,b2,a,b,1} vs W_ss,
// 6..8 = {Sg2,Sgd,Sd2} vs W_vv, 9..14 = {ag,ad,bg,bd,g,d} vs W_sv/W_vs.
__global__ void precompute_coeff(
    const float* __restrict__ Wa_s, const float* __restrict__ Wa_v,
    const float* __restrict__ b_a,  const float* __restrict__ Wb_s,
    const float* __restrict__ Wb_v, const float* __restrict__ b_b,
    const float* __restrict__ W_ss, const float* __restrict__ W_vv,
    const float* __restrict__ W_sv, const float* __restrict__ W_vs,
    float* __restrict__ partial)
{
  __shared__ float As[32], Bs[32], Cc[32], Avv[32], Bvv[32];
  __shared__ float red[8][480];
  const int t = threadIdx.x;                     // 256 threads, 32 blocks
  if (t < 32) {
    As[t] = Wa_s[t]; Bs[t] = Wb_s[t]; Cc[t] = b_a[t] + b_b[t];
    Avv[t] = Wa_v[t]; Bvv[t] = Wb_v[t];
  }
  __syncthreads();
  const int w = t & 31;
  const int grp = t >> 5;
  const int chunk = blockIdx.x * 8 + grp;        // 256 chunks x 4 pairs
  float acc[15];
  #pragma unroll
  for (int k = 0; k < 15; ++k) acc[k] = 0.f;
  #pragma unroll
  for (int j = 0; j < 4; ++j) {
    const int p = chunk * 4 + j;                 // pair = u*32+v
    const int u = p >> 5, v = p & 31;
    const float wss = W_ss[p * 32 + w];
    const float wvv = W_vv[p * 32 + w];
    const float wsv = W_sv[p * 32 + w];
    const float wvs = W_vs[p * 32 + w];
    const float au = As[u], bu = Bs[u], cu = Cc[u], pu = Avv[u], qu = Bvv[u];
    const float av = As[v], bv = Bs[v], cv = Cc[v], pv = Avv[v], qv = Bvv[v];
    acc[0]  = fmaf(au * av, wss, acc[0]);
    acc[1]  = fmaf(au * bv + bu * av, wss, acc[1]);
    acc[2]  = fmaf(bu * bv, wss, acc[2]);
    acc[3]  = fmaf(au * cv + cu * av, wss, acc[3]);
    acc[4]  = fmaf(bu * cv + cu * bv, wss, acc[4]);
    acc[5]  = fmaf(cu * cv, wss, acc[5]);
    acc[6]  = fmaf(pu * pv, wvv, acc[6]);
    acc[7]  = fmaf(pu * qv + qu * pv, wvv, acc[7]);
    acc[8]  = fmaf(qu * qv, wvv, acc[8]);
    acc[9]  = fmaf(au * pv, wsv, fmaf(pu * av, wvs, acc[9]));
    acc[10] = fmaf(au * qv, wsv, fmaf(qu * av, wvs, acc[10]));
    acc[11] = fmaf(bu * pv, wsv, fmaf(pu * bv, wvs, acc[11]));
    acc[12] = fmaf(bu * qv, wsv, fmaf(qu * bv, wvs, acc[12]));
    acc[13] = fmaf(cu * pv, wsv, fmaf(pu * cv, wvs, acc[13]));
    acc[14] = fmaf(cu * qv, wsv, fmaf(qu * cv, wvs, acc[14]));
  }
  #pragma unroll
  for (int k = 0; k < 15; ++k) red[grp][k * 32 + w] = acc[k];
  __syncthreads();
  for (int kk = grp; kk < 15; kk += 8) {
    float s = 0.f;
    #pragma unroll
    for (int b = 0; b < 8; ++b) s += red[b][kk * 32 + w];
    partial[blockIdx.x * 480 + kk * 32 + w] = s;
  }
}

// ---------------- precompute 2: reduce partials, fold through Wd ------
__global__ void precompute_M(
    const float* __restrict__ Wd_s, const float* __restrict__ Wd_v,
    const float* __restrict__ partial,
    float* __restrict__ Ms, float* __restrict__ Mv)
{
  __shared__ float cf[480];
  const int t = threadIdx.x;                     // 512 threads, 1 block
  if (t < 480) {
    float s = 0.f;
    for (int b = 0; b < 32; ++b) s += partial[b * 480 + t];
    cf[t] = s;
  }
  __syncthreads();
  if (t < 128) {
    const int f = t;
    float as[9], av[6];
    #pragma unroll
    for (int k = 0; k < 9; ++k) as[k] = 0.f;
    #pragma unroll
    for (int k = 0; k < 6; ++k) av[k] = 0.f;
    for (int w = 0; w < 32; ++w) {
      const float wds = Wd_s[w * 128 + f];
      const float wdv = Wd_v[w * 128 + f];
      #pragma unroll
      for (int k = 0; k < 9; ++k) as[k] = fmaf(cf[k * 32 + w], wds, as[k]);
      #pragma unroll
      for (int k = 0; k < 6; ++k) av[k] = fmaf(cf[(9 + k) * 32 + w], wdv, av[k]);
    }
    const float sP = 1.0f / 4096.0f;                        // PW_DOWN*PW_QQ_S
    const float sQ = 0.57735026918962576451f / 4096.0f;     // *INV_SQRT3
    #pragma unroll
    for (int k = 0; k < 6; ++k) Ms[f * 16 + k] = as[k] * sP;
    #pragma unroll
    for (int k = 0; k < 3; ++k) Ms[f * 16 + 6 + k] = as[6 + k] * sQ;
    #pragma unroll
    for (int k = 0; k < 6; ++k) Mv[f * 8 + k] = av[k] * sQ;
  }
}

// ---------------- main kernel: direct-streaming, 32 lanes / node ------
// Lane s (=t&31) owns features f in [4s, 4s+4):
//   s-region : floats [4s*.. ]      -> float4 index  s          (dense)
//   v-region : floats 128+[12s,+12) -> float4 index 32+3s+{0,1,2}
// 12s == 0 (mod 3), so each lane holds only WHOLE features and the
// component index i = q%3 is a compile-time pattern. Coefficients
// Ms[f][0..8], Mv[f][0..5] for the lane's 4 features are loop-invariant
// -> 60 registers loaded once. Per node: 4 nf float4 loads + 2 charge
// loads (group-uniform address, L1 broadcast), ~110 VALU, 5 shfl_xor.
__global__ __launch_bounds__(TBLK) void energy_main(
    const float* __restrict__ nf,
    const float* __restrict__ ch0,
    const float* __restrict__ chi,
    const float* __restrict__ Ms,
    const float* __restrict__ Mv,
    float* __restrict__ out)
{
  const int t    = threadIdx.x;
  const int s32  = t & 31;          // lane within the 32-lane node group
  const int gidx = t >> 5;          // 0..7: node slot within a pass

  // ---- per-lane loop-invariant coefficients ----
  float ms[4][9];
  float mv[4][6];
  {
    const float4* Ms4 = reinterpret_cast<const float4*>(Ms);  // [128][4]
    const float4* Mv4 = reinterpret_cast<const float4*>(Mv);  // [128][2]
    #pragma unroll
    for (int fl = 0; fl < 4; ++fl) {
      const int f = 4 * s32 + fl;
      const float4 a = Ms4[f * 4 + 0];
      const float4 b = Ms4[f * 4 + 1];
      const float4 c = Ms4[f * 4 + 2];
      ms[fl][0] = a.x; ms[fl][1] = a.y; ms[fl][2] = a.z; ms[fl][3] = a.w;
      ms[fl][4] = b.x; ms[fl][5] = b.y; ms[fl][6] = b.z; ms[fl][7] = b.w;
      ms[fl][8] = c.x;
      const float4 u = Mv4[f * 2 + 0];
      const float4 v = Mv4[f * 2 + 1];
      mv[fl][0] = u.x; mv[fl][1] = u.y; mv[fl][2] = u.z; mv[fl][3] = u.w;
      mv[fl][4] = v.x; mv[fl][5] = v.y;
    }
  }

  const float4* nf4 = reinterpret_cast<const float4*>(nf);
  const float4* c04 = reinterpret_cast<const float4*>(ch0);
  const float4* ci4 = reinterpret_cast<const float4*>(chi);

  const int node0 = blockIdx.x * NPB;

  #pragma unroll 2
  for (int p = 0; p < PASSES; ++p) {
    const int node  = node0 + p * NODES_PER_PASS + gidx;
    const size_t rb = (size_t)node * 128;        // float4 row base

    const float4 cc0 = c04[node];                // group-uniform address
    const float4 cci = ci4[node];
    const float4 xs  = nf4[rb + s32];
    const float4 xv0 = nf4[rb + 32 + 3 * s32 + 0];
    const float4 xv1 = nf4[rb + 32 + 3 * s32 + 1];
    const float4 xv2 = nf4[rb + 32 + 3 * s32 + 2];

    const float alpha = cci.x, g0 = cci.y, g1 = cci.z, g2 = cci.w;
    const float beta  = cc0.x, d0 = cc0.y, d1 = cc0.z, d2 = cc0.w;
    const float m0 = alpha * alpha, m1 = alpha * beta, m2 = beta * beta;
    const float m6 = fmaf(g0, g0, fmaf(g1, g1, g2 * g2));
    const float m7 = fmaf(g0, d0, fmaf(g1, d1, g2 * d2));
    const float m8 = fmaf(d0, d0, fmaf(d1, d1, d2 * d2));

    float e = 0.f;

    // ---- s-region: 4 features (one float4) ----
    const float xse[4] = {xs.x, xs.y, xs.z, xs.w};
    #pragma unroll
    for (int fl = 0; fl < 4; ++fl) {
      float r = ms[fl][5];
      r = fmaf(m0,    ms[fl][0], r);
      r = fmaf(m1,    ms[fl][1], r);
      r = fmaf(m2,    ms[fl][2], r);
      r = fmaf(alpha, ms[fl][3], r);
      r = fmaf(beta,  ms[fl][4], r);
      r = fmaf(m6,    ms[fl][6], r);
      r = fmaf(m7,    ms[fl][7], r);
      r = fmaf(m8,    ms[fl][8], r);
      e = fmaf(xse[fl], r, e);
    }

    // ---- v-region: 12 floats = 4 whole features, phases compile-time --
    const float xve[12] = {xv0.x, xv0.y, xv0.z, xv0.w,
                           xv1.x, xv1.y, xv1.z, xv1.w,
                           xv2.x, xv2.y, xv2.z, xv2.w};
    const float gg[3] = {g0, g1, g2};
    const float dd[3] = {d0, d1, d2};
    float P = 0.f, Q = 0.f;
    #pragma unroll
    for (int q = 0; q < 12; ++q) {
      const int i = q % 3;                       // compile-time on unroll
      P = fmaf(gg[i], xve[q], P);
      Q = fmaf(dd[i], xve[q], Q);
      if (i == 2) {                              // feature complete
        const int fl = q / 3;
        const float wP = fmaf(alpha, mv[fl][0], fmaf(beta, mv[fl][2], mv[fl][4]));
        const float wQ = fmaf(alpha, mv[fl][1], fmaf(beta, mv[fl][3], mv[fl][5]));
        e = fmaf(P, wP, fmaf(Q, wQ, e));
        P = 0.f; Q = 0.f;
      }
    }

    // ---- reduce across the 32-lane group (xor<=16 stays in half) ----
    e += __shfl_xor(e, 1);
    e += __shfl_xor(e, 2);
    e += __shfl_xor(e, 4);
    e += __shfl_xor(e, 8);
    e += __shfl_xor(e, 16);
    if (s32 == 0) out[node] = e;
  }
}

// ---------------- launcher -------------------------------------------
extern "C" void kernel_launch(void* const* d_in, const int* in_sizes, int n_in,
                              void* d_out, int out_size, void* d_ws, size_t ws_size,
                              hipStream_t stream)
{
  const float* node_feats      = (const float*)d_in[0];
  const float* charges_0       = (const float*)d_in[1];
  const float* charges_induced = (const float*)d_in[2];
  const float* Wa_s = (const float*)d_in[8];
  const float* Wa_v = (const float*)d_in[9];
  const float* b_a  = (const float*)d_in[10];
  const float* Wb_s = (const float*)d_in[11];
  const float* Wb_v = (const float*)d_in[12];
  const float* b_b  = (const float*)d_in[13];
  const float* W_ss = (const float*)d_in[14];
  const float* W_vv = (const float*)d_in[15];
  const float* W_sv = (const float*)d_in[16];
  const float* W_vs = (const float*)d_in[17];
  const float* Wd_s = (const float*)d_in[18];
  const float* Wd_v = (const float*)d_in[19];

  float* ws      = (float*)d_ws;
  float* Ms      = ws;              // [128][16] = 2048 floats
  float* Mv      = ws + 2048;       // [128][8]  = 1024 floats
  float* partial = ws + 3072;       // [32][15][32] = 15360 floats

  precompute_coeff<<<32, 256, 0, stream>>>(Wa_s, Wa_v, b_a, Wb_s, Wb_v, b_b,
                                           W_ss, W_vv, W_sv, W_vs, partial);
  precompute_M<<<1, 512, 0, stream>>>(Wd_s, Wd_v, partial, Ms, Mv);
  energy_main<<<NNODES / NPB, TBLK, 0, stream>>>(node_feats, charges_0,
                                                 charges_induced, Ms, Mv,
                                                 (float*)d_out);
}

// Round 2
// 404.791 us; speedup vs baseline: 1.0746x; 1.0197x over previous
//
#include <hip/hip_runtime.h>

// =====================================================================
// QuadraticChargesEnergyReadout — R5: explicit cross-pass prefetch.
// R4 (direct streaming, unroll 2) left energy_main at ~150 us (~1.8
// TB/s): #pragma unroll 2 only overlaps loads WITHIN each 2-pass
// window; at every window boundary the next loads issue only after the
// previous compute, exposing ~900-cycle HBM latency per wave every 2
// passes. R5 software-pipelines explicitly: a rotating prefetch
// register set + full unroll of the 8-pass loop, so pass p+1's 6 loads
// (4x nf float4 + 2 charge float4) are in flight before pass p's
// compute waits on vmcnt. __launch_bounds__(256,2) caps VGPR at 128 to
// keep the 16-waves/CU occupancy tier.
// Memory-bound floor: ~271 MB traffic -> ~43 us.
// =====================================================================

#define NNODES 131072
#define TBLK 256
#define NODES_PER_PASS 8          // (TBLK/32) nodes per block-pass
#define PASSES 8
#define NPB (NODES_PER_PASS * PASSES)   // 64 nodes per block

// ---------------- precompute 1: per-block partial coefficients --------
// partial[b][k][w], k 0..5 = s.s monomials {a2,ab,b2,a,b,1} vs W_ss,
// 6..8 = {Sg2,Sgd,Sd2} vs W_vv, 9..14 = {ag,ad,bg,bd,g,d} vs W_sv/W_vs.
__global__ void precompute_coeff(
    const float* __restrict__ Wa_s, const float* __restrict__ Wa_v,
    const float* __restrict__ b_a,  const float* __restrict__ Wb_s,
    const float* __restrict__ Wb_v, const float* __restrict__ b_b,
    const float* __restrict__ W_ss, const float* __restrict__ W_vv,
    const float* __restrict__ W_sv, const float* __restrict__ W_vs,
    float* __restrict__ partial)
{
  __shared__ float As[32], Bs[32], Cc[32], Avv[32], Bvv[32];
  __shared__ float red[8][480];
  const int t = threadIdx.x;                     // 256 threads, 32 blocks
  if (t < 32) {
    As[t] = Wa_s[t]; Bs[t] = Wb_s[t]; Cc[t] = b_a[t] + b_b[t];
    Avv[t] = Wa_v[t]; Bvv[t] = Wb_v[t];
  }
  __syncthreads();
  const int w = t & 31;
  const int grp = t >> 5;
  const int chunk = blockIdx.x * 8 + grp;        // 256 chunks x 4 pairs
  float acc[15];
  #pragma unroll
  for (int k = 0; k < 15; ++k) acc[k] = 0.f;
  #pragma unroll
  for (int j = 0; j < 4; ++j) {
    const int p = chunk * 4 + j;                 // pair = u*32+v
    const int u = p >> 5, v = p & 31;
    const float wss = W_ss[p * 32 + w];
    const float wvv = W_vv[p * 32 + w];
    const float wsv = W_sv[p * 32 + w];
    const float wvs = W_vs[p * 32 + w];
    const float au = As[u], bu = Bs[u], cu = Cc[u], pu = Avv[u], qu = Bvv[u];
    const float av = As[v], bv = Bs[v], cv = Cc[v], pv = Avv[v], qv = Bvv[v];
    acc[0]  = fmaf(au * av, wss, acc[0]);
    acc[1]  = fmaf(au * bv + bu * av, wss, acc[1]);
    acc[2]  = fmaf(bu * bv, wss, acc[2]);
    acc[3]  = fmaf(au * cv + cu * av, wss, acc[3]);
    acc[4]  = fmaf(bu * cv + cu * bv, wss, acc[4]);
    acc[5]  = fmaf(cu * cv, wss, acc[5]);
    acc[6]  = fmaf(pu * pv, wvv, acc[6]);
    acc[7]  = fmaf(pu * qv + qu * pv, wvv, acc[7]);
    acc[8]  = fmaf(qu * qv, wvv, acc[8]);
    acc[9]  = fmaf(au * pv, wsv, fmaf(pu * av, wvs, acc[9]));
    acc[10] = fmaf(au * qv, wsv, fmaf(qu * av, wvs, acc[10]));
    acc[11] = fmaf(bu * pv, wsv, fmaf(pu * bv, wvs, acc[11]));
    acc[12] = fmaf(bu * qv, wsv, fmaf(qu * bv, wvs, acc[12]));
    acc[13] = fmaf(cu * pv, wsv, fmaf(pu * cv, wvs, acc[13]));
    acc[14] = fmaf(cu * qv, wsv, fmaf(qu * cv, wvs, acc[14]));
  }
  #pragma unroll
  for (int k = 0; k < 15; ++k) red[grp][k * 32 + w] = acc[k];
  __syncthreads();
  for (int kk = grp; kk < 15; kk += 8) {
    float s = 0.f;
    #pragma unroll
    for (int b = 0; b < 8; ++b) s += red[b][kk * 32 + w];
    partial[blockIdx.x * 480 + kk * 32 + w] = s;
  }
}

// ---------------- precompute 2: reduce partials, fold through Wd ------
__global__ void precompute_M(
    const float* __restrict__ Wd_s, const float* __restrict__ Wd_v,
    const float* __restrict__ partial,
    float* __restrict__ Ms, float* __restrict__ Mv)
{
  __shared__ float cf[480];
  const int t = threadIdx.x;                     // 512 threads, 1 block
  if (t < 480) {
    float s = 0.f;
    for (int b = 0; b < 32; ++b) s += partial[b * 480 + t];
    cf[t] = s;
  }
  __syncthreads();
  if (t < 128) {
    const int f = t;
    float as[9], av[6];
    #pragma unroll
    for (int k = 0; k < 9; ++k) as[k] = 0.f;
    #pragma unroll
    for (int k = 0; k < 6; ++k) av[k] = 0.f;
    for (int w = 0; w < 32; ++w) {
      const float wds = Wd_s[w * 128 + f];
      const float wdv = Wd_v[w * 128 + f];
      #pragma unroll
      for (int k = 0; k < 9; ++k) as[k] = fmaf(cf[k * 32 + w], wds, as[k]);
      #pragma unroll
      for (int k = 0; k < 6; ++k) av[k] = fmaf(cf[(9 + k) * 32 + w], wdv, av[k]);
    }
    const float sP = 1.0f / 4096.0f;                        // PW_DOWN*PW_QQ_S
    const float sQ = 0.57735026918962576451f / 4096.0f;     // *INV_SQRT3
    #pragma unroll
    for (int k = 0; k < 6; ++k) Ms[f * 16 + k] = as[k] * sP;
    #pragma unroll
    for (int k = 0; k < 3; ++k) Ms[f * 16 + 6 + k] = as[6 + k] * sQ;
    #pragma unroll
    for (int k = 0; k < 6; ++k) Mv[f * 8 + k] = av[k] * sQ;
  }
}

// ---------------- main kernel: streamed, 1-pass-deep prefetch ---------
// Lane s (=t&31) owns features f in [4s, 4s+4):
//   s-region : float4 index  s (dense across lanes)
//   v-region : float4 index 32+3s+{0,1,2} (contiguous per lane; the
//              128B-line overlap across the 3 instrs hits in L1)
// Coefficients Ms[f][0..8], Mv[f][0..5] for the lane's 4 features are
// loop-invariant -> 60 registers loaded once. The pass loop is FULLY
// unrolled with a rotating prefetch set: pass p+1's 6 loads are issued
// before pass p's compute, so the vmcnt wait for p always has p+1's
// loads already in flight (no latency window at any pass boundary).
__global__ __launch_bounds__(TBLK, 2) void energy_main(
    const float* __restrict__ nf,
    const float* __restrict__ ch0,
    const float* __restrict__ chi,
    const float* __restrict__ Ms,
    const float* __restrict__ Mv,
    float* __restrict__ out)
{
  const int t    = threadIdx.x;
  const int s32  = t & 31;          // lane within the 32-lane node group
  const int gidx = t >> 5;          // 0..7: node slot within a pass

  // ---- per-lane loop-invariant coefficients ----
  float ms[4][9];
  float mv[4][6];
  {
    const float4* Ms4 = reinterpret_cast<const float4*>(Ms);  // [128][4]
    const float4* Mv4 = reinterpret_cast<const float4*>(Mv);  // [128][2]
    #pragma unroll
    for (int fl = 0; fl < 4; ++fl) {
      const int f = 4 * s32 + fl;
      const float4 a = Ms4[f * 4 + 0];
      const float4 b = Ms4[f * 4 + 1];
      const float4 c = Ms4[f * 4 + 2];
      ms[fl][0] = a.x; ms[fl][1] = a.y; ms[fl][2] = a.z; ms[fl][3] = a.w;
      ms[fl][4] = b.x; ms[fl][5] = b.y; ms[fl][6] = b.z; ms[fl][7] = b.w;
      ms[fl][8] = c.x;
      const float4 u = Mv4[f * 2 + 0];
      const float4 v = Mv4[f * 2 + 1];
      mv[fl][0] = u.x; mv[fl][1] = u.y; mv[fl][2] = u.z; mv[fl][3] = u.w;
      mv[fl][4] = v.x; mv[fl][5] = v.y;
    }
  }

  const float4* nf4 = reinterpret_cast<const float4*>(nf);
  const float4* c04 = reinterpret_cast<const float4*>(ch0);
  const float4* ci4 = reinterpret_cast<const float4*>(chi);

  const int node0 = blockIdx.x * NPB;

  // ---- prologue: prefetch pass 0 ----
  float4 pxs, pv0, pv1, pv2, pc0, pci;
  {
    const int node  = node0 + gidx;
    const size_t rb = (size_t)node * 128;
    pc0 = c04[node];
    pci = ci4[node];
    pxs = nf4[rb + s32];
    pv0 = nf4[rb + 32 + 3 * s32 + 0];
    pv1 = nf4[rb + 32 + 3 * s32 + 1];
    pv2 = nf4[rb + 32 + 3 * s32 + 2];
  }

  #pragma unroll
  for (int p = 0; p < PASSES; ++p) {
    // consume current prefetch set (SSA-renamed under full unroll; the
    // vmcnt wait for these lands after the NEXT pass's loads are issued)
    const float4 xs  = pxs;
    const float4 xv0 = pv0;
    const float4 xv1 = pv1;
    const float4 xv2 = pv2;
    const float4 cc0 = pc0;
    const float4 cci = pci;

    // ---- issue next pass's loads before computing this pass ----
    if (p + 1 < PASSES) {
      const int nn    = node0 + (p + 1) * NODES_PER_PASS + gidx;
      const size_t rb = (size_t)nn * 128;
      pc0 = c04[nn];
      pci = ci4[nn];
      pxs = nf4[rb + s32];
      pv0 = nf4[rb + 32 + 3 * s32 + 0];
      pv1 = nf4[rb + 32 + 3 * s32 + 1];
      pv2 = nf4[rb + 32 + 3 * s32 + 2];
    }

    const int node = node0 + p * NODES_PER_PASS + gidx;

    const float alpha = cci.x, g0 = cci.y, g1 = cci.z, g2 = cci.w;
    const float beta  = cc0.x, d0 = cc0.y, d1 = cc0.z, d2 = cc0.w;
    const float m0 = alpha * alpha, m1 = alpha * beta, m2 = beta * beta;
    const float m6 = fmaf(g0, g0, fmaf(g1, g1, g2 * g2));
    const float m7 = fmaf(g0, d0, fmaf(g1, d1, g2 * d2));
    const float m8 = fmaf(d0, d0, fmaf(d1, d1, d2 * d2));

    float e = 0.f;

    // ---- s-region: 4 features (one float4) ----
    const float xse[4] = {xs.x, xs.y, xs.z, xs.w};
    #pragma unroll
    for (int fl = 0; fl < 4; ++fl) {
      float r = ms[fl][5];
      r = fmaf(m0,    ms[fl][0], r);
      r = fmaf(m1,    ms[fl][1], r);
      r = fmaf(m2,    ms[fl][2], r);
      r = fmaf(alpha, ms[fl][3], r);
      r = fmaf(beta,  ms[fl][4], r);
      r = fmaf(m6,    ms[fl][6], r);
      r = fmaf(m7,    ms[fl][7], r);
      r = fmaf(m8,    ms[fl][8], r);
      e = fmaf(xse[fl], r, e);
    }

    // ---- v-region: 12 floats = 4 whole features, phases compile-time --
    const float xve[12] = {xv0.x, xv0.y, xv0.z, xv0.w,
                           xv1.x, xv1.y, xv1.z, xv1.w,
                           xv2.x, xv2.y, xv2.z, xv2.w};
    const float gg[3] = {g0, g1, g2};
    const float dd[3] = {d0, d1, d2};
    float P = 0.f, Q = 0.f;
    #pragma unroll
    for (int q = 0; q < 12; ++q) {
      const int i = q % 3;                       // compile-time on unroll
      P = fmaf(gg[i], xve[q], P);
      Q = fmaf(dd[i], xve[q], Q);
      if (i == 2) {                              // feature complete
        const int fl = q / 3;
        const float wP = fmaf(alpha, mv[fl][0], fmaf(beta, mv[fl][2], mv[fl][4]));
        const float wQ = fmaf(alpha, mv[fl][1], fmaf(beta, mv[fl][3], mv[fl][5]));
        e = fmaf(P, wP, fmaf(Q, wQ, e));
        P = 0.f; Q = 0.f;
      }
    }

    // ---- reduce across the 32-lane group ----
    e += __shfl_xor(e, 1);
    e += __shfl_xor(e, 2);
    e += __shfl_xor(e, 4);
    e += __shfl_xor(e, 8);
    e += __shfl_xor(e, 16);
    if (s32 == 0) out[node] = e;
  }
}

// ---------------- launcher -------------------------------------------
extern "C" void kernel_launch(void* const* d_in, const int* in_sizes, int n_in,
                              void* d_out, int out_size, void* d_ws, size_t ws_size,
                              hipStream_t stream)
{
  const float* node_feats      = (const float*)d_in[0];
  const float* charges_0       = (const float*)d_in[1];
  const float* charges_induced = (const float*)d_in[2];
  const float* Wa_s = (const float*)d_in[8];
  const float* Wa_v = (const float*)d_in[9];
  const float* b_a  = (const float*)d_in[10];
  const float* Wb_s = (const float*)d_in[11];
  const float* Wb_v = (const float*)d_in[12];
  const float* b_b  = (const float*)d_in[13];
  const float* W_ss = (const float*)d_in[14];
  const float* W_vv = (const float*)d_in[15];
  const float* W_sv = (const float*)d_in[16];
  const float* W_vs = (const float*)d_in[17];
  const float* Wd_s = (const float*)d_in[18];
  const float* Wd_v = (const float*)d_in[19];

  float* ws      = (float*)d_ws;
  float* Ms      = ws;              // [128][16] = 2048 floats
  float* Mv      = ws + 2048;       // [128][8]  = 1024 floats
  float* partial = ws + 3072;       // [32][15][32] = 15360 floats

  precompute_coeff<<<32, 256, 0, stream>>>(Wa_s, Wa_v, b_a, Wb_s, Wb_v, b_b,
                                           W_ss, W_vv, W_sv, W_vs, partial);
  precompute_M<<<1, 512, 0, stream>>>(Wd_s, Wd_v, partial, Ms, Mv);
  energy_main<<<NNODES / NPB, TBLK, 0, stream>>>(node_feats, charges_0,
                                                 charges_induced, Ms, Mv,
                                                 (float*)d_out);
}